// Round 7
// baseline (19621.800 us; speedup 1.0000x reference)
//
#include <hip/hip_runtime.h>
#include <hip/hip_bf16.h>
#include <stdint.h>

// E60bGatedResidualCell — R7: outputs are FP32 (npz-size evidence), fp32 recurrence,
// split-bf16 MFMA projections (fp32-accurate to ~2^-16) into fp32 P/G.
// out[t] = h²σ(h); h_{t+1} = h_t + g_t ⊙ tanh(h_t W_hᵀ + x_t W_xᵀ + b)

#define T_DIM 512
#define B_DIM 32
#define D_DIM 1024
#define M_DIM (T_DIM*B_DIM)

typedef __attribute__((ext_vector_type(4))) float f32x4;
typedef __attribute__((ext_vector_type(8))) short bf16x8;

__device__ inline unsigned short f2b(float f){
  union { float f; uint32_t u; } c; c.f = f;
  uint32_t u = c.u + 0x7fffu + ((c.u >> 16) & 1u);   // RNE
  return (unsigned short)(u >> 16);
}
__device__ inline float b2f(unsigned short h){
  union { uint32_t u; float f; } c; c.u = ((uint32_t)h) << 16;
  return c.f;
}

// ---- init: h[0] plane of output (fp32 zeros) + fp32 h ping-pong slot 0 --------
__global__ void init_kernel(float* __restrict__ out_h0, float* __restrict__ h0){
  int i = blockIdx.x*blockDim.x + threadIdx.x;   // 32768 threads
  out_h0[i] = 0.f;
  h0[i] = 0.f;
}

// ---- proj (split-bf16 MFMA, fp32 out): OUT[m,n] = f(sum_k X[m,k]*W[n,k]+bias) -
// acc = Xhi·Whi + Xhi·Wlo + Xlo·Whi  (residual ~2^-16 rel)
template<int MODE>
__global__ __launch_bounds__(256, 2)
void proj_m(const float* __restrict__ X, const float* __restrict__ W,
            const float* __restrict__ bias, float* __restrict__ OUT)
{
  __shared__ unsigned short Ah[128*64];
  __shared__ unsigned short Al[128*64];
  __shared__ unsigned short Bh[128*64];
  __shared__ unsigned short Bl[128*64];
  char* AhB=(char*)Ah; char* AlB=(char*)Al; char* BhB=(char*)Bh; char* BlB=(char*)Bl;
  const int tid  = threadIdx.x;
  const int lane = tid & 63;
  const int wave = tid >> 6;
  const int m0 = blockIdx.y * 128;
  const int n0 = blockIdx.x * 128;
  const int wm = (wave >> 1) * 64;
  const int wn = (wave & 1) * 64;
  const int fr = lane & 15;
  const int fq = lane >> 4;

  f32x4 acc[4][4];
  #pragma unroll
  for (int i=0;i<4;++i)
    #pragma unroll
    for (int j=0;j<4;++j) acc[i][j] = (f32x4){0.f,0.f,0.f,0.f};

  for (int kt = 0; kt < D_DIM/64; ++kt) {
    #pragma unroll
    for (int c = 0; c < 4; ++c) {
      int idx = tid + c*256;         // 0..1023 : 128 rows x 8 chunks
      int row = idx >> 3;
      int k8  = idx & 7;
      const float* ga = X + (size_t)(m0+row)*D_DIM + kt*64 + k8*8;
      const float* gb = W + (size_t)(n0+row)*D_DIM + kt*64 + k8*8;
      f32x4 a0 = *(const f32x4*)ga, a1 = *(const f32x4*)(ga+4);
      f32x4 b0 = *(const f32x4*)gb, b1 = *(const f32x4*)(gb+4);
      bf16x8 vah, val, vbh, vbl;
      #pragma unroll
      for (int j=0;j<4;++j){
        unsigned short h;
        h = f2b(a0[j]); vah[j]   = (short)h; val[j]   = (short)f2b(a0[j]-b2f(h));
        h = f2b(a1[j]); vah[4+j] = (short)h; val[4+j] = (short)f2b(a1[j]-b2f(h));
        h = f2b(b0[j]); vbh[j]   = (short)h; vbl[j]   = (short)f2b(b0[j]-b2f(h));
        h = f2b(b1[j]); vbh[4+j] = (short)h; vbl[4+j] = (short)f2b(b1[j]-b2f(h));
      }
      int lb = row*128 + ((k8*16) ^ ((row&7)<<4));   // XOR-swizzle (T2)
      *(bf16x8*)(AhB + lb) = vah;
      *(bf16x8*)(AlB + lb) = val;
      *(bf16x8*)(BhB + lb) = vbh;
      *(bf16x8*)(BlB + lb) = vbl;
    }
    __syncthreads();
    #pragma unroll
    for (int kk=0; kk<2; ++kk) {
      bf16x8 afh[4], afl[4], bfh[4], bfl[4];
      #pragma unroll
      for (int i=0;i<4;++i){
        int row = wm+i*16+fr;
        int off = row*128 + ((kk*64 + fq*16) ^ ((row&7)<<4));
        afh[i] = *(const bf16x8*)(AhB + off);
        afl[i] = *(const bf16x8*)(AlB + off);
      }
      #pragma unroll
      for (int j=0;j<4;++j){
        int row = wn+j*16+fr;
        int off = row*128 + ((kk*64 + fq*16) ^ ((row&7)<<4));
        bfh[j] = *(const bf16x8*)(BhB + off);
        bfl[j] = *(const bf16x8*)(BlB + off);
      }
      #pragma unroll
      for (int i=0;i<4;++i)
        #pragma unroll
        for (int j=0;j<4;++j){
          acc[i][j] = __builtin_amdgcn_mfma_f32_16x16x32_bf16(afh[i], bfh[j], acc[i][j], 0,0,0);
          acc[i][j] = __builtin_amdgcn_mfma_f32_16x16x32_bf16(afh[i], bfl[j], acc[i][j], 0,0,0);
          acc[i][j] = __builtin_amdgcn_mfma_f32_16x16x32_bf16(afl[i], bfh[j], acc[i][j], 0,0,0);
        }
    }
    __syncthreads();
  }
  #pragma unroll
  for (int j=0;j<4;++j) {
    int col = n0 + wn + j*16 + fr;
    float bv = bias[col];
    #pragma unroll
    for (int i=0;i<4;++i) {
      int rowb = m0 + wm + i*16 + fq*4;
      #pragma unroll
      for (int r=0;r<4;++r) {
        float v = acc[i][j][r] + bv;
        if (MODE==1) v = 1.f/(1.f + expf(-v));
        OUT[(size_t)(rowb+r)*D_DIM + col] = v;
      }
    }
  }
}

// ---- one recurrence step (Path A: fp32 P/G from ws) ---------------------------
__global__ __launch_bounds__(256)
void rnn_stepA(int t, const float* __restrict__ Wh,
               const float* __restrict__ P,
               const float* __restrict__ G,
               const float* __restrict__ h_prev,
               float* __restrict__ h_next,
               float* __restrict__ out_o,
               float* __restrict__ out_h)
{
  int g = blockIdx.x*256 + threadIdx.x;      // 0 .. 32767
  int b = g >> 10;

  const f32x4* h4 = (const f32x4*)(h_prev + (size_t)b*D_DIM);
  const f32x4* w4 = (const f32x4*)(Wh + (size_t)(g & 1023)*D_DIM);
  float acc = 0.f;
  #pragma unroll 4
  for (int k = 0; k < D_DIM/4; ++k) {
    f32x4 a = h4[k], w = w4[k];
    acc += a[0]*w[0] + a[1]*w[1] + a[2]*w[2] + a[3]*w[3];
  }

  size_t idx = (size_t)t*(B_DIM*D_DIM) + g;
  float pre = acc + P[idx];
  float th = tanhf(pre);
  float hn = h_prev[g] + G[idx]*th;
  float sg = 1.f/(1.f + expf(-hn));
  out_o[idx] = hn*hn*sg;                           // out[t]
  out_h[idx + (size_t)(B_DIM*D_DIM)] = hn;         // h[t+1]
  h_next[g] = hn;
}

// ---- one recurrence step (Path B: recompute wx/g inline; small-ws fallback) ---
__global__ __launch_bounds__(256)
void rnn_stepB(int t, const float* __restrict__ Wh,
               const float* __restrict__ X,
               const float* __restrict__ Wx,
               const float* __restrict__ Wg,
               const float* __restrict__ bias,
               const float* __restrict__ bias_g,
               const float* __restrict__ h_prev,
               float* __restrict__ h_next,
               float* __restrict__ out_o,
               float* __restrict__ out_h)
{
  int g = blockIdx.x*256 + threadIdx.x;      // 0 .. 32767
  int b = g >> 10;
  int e = g & 1023;

  const f32x4* h4 = (const f32x4*)(h_prev + (size_t)b*D_DIM);
  const f32x4* x4 = (const f32x4*)(X + (size_t)t*(B_DIM*D_DIM) + (size_t)b*D_DIM);
  const f32x4* wh4 = (const f32x4*)(Wh + (size_t)e*D_DIM);
  const f32x4* wx4 = (const f32x4*)(Wx + (size_t)e*D_DIM);
  const f32x4* wg4 = (const f32x4*)(Wg + (size_t)e*D_DIM);
  float ah = 0.f, ax = 0.f, ag = 0.f;
  #pragma unroll 2
  for (int k = 0; k < D_DIM/4; ++k) {
    f32x4 hv = h4[k], xv = x4[k];
    f32x4 a = wh4[k], c = wx4[k], d = wg4[k];
    ah += hv[0]*a[0] + hv[1]*a[1] + hv[2]*a[2] + hv[3]*a[3];
    ax += xv[0]*c[0] + xv[1]*c[1] + xv[2]*c[2] + xv[3]*c[3];
    ag += xv[0]*d[0] + xv[1]*d[1] + xv[2]*d[2] + xv[3]*d[3];
  }

  size_t idx = (size_t)t*(B_DIM*D_DIM) + g;
  float gg = 1.f/(1.f + expf(-(ag + bias_g[e])));
  float pre = ah + ax + bias[e];
  float th = tanhf(pre);
  float hn = h_prev[g] + gg*th;
  float sg = 1.f/(1.f + expf(-hn));
  out_o[idx] = hn*hn*sg;
  out_h[idx + (size_t)(B_DIM*D_DIM)] = hn;
  h_next[g] = hn;
}

extern "C" void kernel_launch(void* const* d_in, const int* in_sizes, int n_in,
                              void* d_out, int out_size, void* d_ws, size_t ws_size,
                              hipStream_t stream) {
  const float* x  = (const float*)d_in[0];
  const float* Wh = (const float*)d_in[1];
  const float* Wx = (const float*)d_in[2];
  const float* Wg = (const float*)d_in[3];
  const float* b  = (const float*)d_in[4];
  const float* bg = (const float*)d_in[5];

  float* out_o = (float*)d_out;                       // [T,B,D] fp32
  float* out_h = out_o + (size_t)M_DIM*D_DIM;         // [T+1,B,D] fp32

  const size_t PG_BYTES = (size_t)M_DIM * D_DIM * 4;  // 64 MiB each
  const size_t H_BYTES  = (size_t)B_DIM * D_DIM * 4;  // 128 KiB each
  char* ws = (char*)d_ws;

  bool bigws = (ws_size >= 2*PG_BYTES + 2*H_BYTES);

  float* P  = (float*)ws;
  float* G  = (float*)(ws + PG_BYTES);
  float* h0 = bigws ? (float*)(ws + 2*PG_BYTES) : (float*)ws;
  float* h1 = h0 + B_DIM*D_DIM;

  init_kernel<<<128, 256, 0, stream>>>(out_h, h0);

  if (bigws) {
    proj_m<0><<<dim3(8,128), 256, 0, stream>>>(x, Wx, b,  P);
    proj_m<1><<<dim3(8,128), 256, 0, stream>>>(x, Wg, bg, G);
    for (int t = 0; t < T_DIM; ++t) {
      float* hp = (t & 1) ? h1 : h0;
      float* hn = (t & 1) ? h0 : h1;
      rnn_stepA<<<(B_DIM*D_DIM)/256, 256, 0, stream>>>(t, Wh, P, G, hp, hn, out_o, out_h);
    }
  } else {
    for (int t = 0; t < T_DIM; ++t) {
      float* hp = (t & 1) ? h1 : h0;
      float* hn = (t & 1) ? h0 : h1;
      rnn_stepB<<<(B_DIM*D_DIM)/256, 256, 0, stream>>>(t, Wh, x, Wx, Wg, b, bg, hp, hn, out_o, out_h);
    }
  }
}

// Round 8
// 9689.982 us; speedup vs baseline: 2.0250x; 2.0250x over previous
//
#include <hip/hip_runtime.h>
#include <hip/hip_bf16.h>
#include <stdint.h>

// E60bGatedResidualCell — R8: persistent recurrence, register-resident Wh.
// out[t] = h²σ(h); h_{t+1} = h_t + g_t ⊙ tanh(h_t W_hᵀ + x_t W_xᵀ + b)
// fp32 outputs. P = x@Wxᵀ+b stored in out_h[t+1] (read@t before overwrite);
// G = σ(x@Wgᵀ+bg) stored in out_o[t] (same). d_ws: h_ex (256KB) + flags (16KB).
// 256 persistent WGs = 4 chain-groups (8 b) × 64 e-slices (16 e). Wh in VGPRs
// (64 f32/thread, loaded once). Cross-WG h via agent-scope atomics + flags.

#define T_DIM 512
#define B_DIM 32
#define D_DIM 1024
#define M_DIM (T_DIM*B_DIM)

typedef __attribute__((ext_vector_type(4))) float f32x4;
typedef __attribute__((ext_vector_type(8))) short bf16x8;

__device__ inline unsigned short f2b(float f){
  union { float f; uint32_t u; } c; c.f = f;
  uint32_t u = c.u + 0x7fffu + ((c.u >> 16) & 1u);   // RNE
  return (unsigned short)(u >> 16);
}
__device__ inline float b2f(unsigned short h){
  union { uint32_t u; float f; } c; c.u = ((uint32_t)h) << 16;
  return c.f;
}

// ---- init: zero out_h[0], h_ex buf0 (all groups), flags -----------------------
__global__ void init_kernel(float* __restrict__ out_h0,
                            float* __restrict__ h_ex,
                            uint32_t* __restrict__ flags){
  int i = blockIdx.x*blockDim.x + threadIdx.x;   // 0..32767
  out_h0[i] = 0.f;
  int g = i >> 13, j = i & 8191;
  h_ex[(size_t)g*16384 + j] = 0.f;               // buf0 of each group
  if (i < 4096) flags[i] = 0;
}

// ---- proj (split-bf16 MFMA, fp32 out): OUT[m,n] = f(sum_k X[m,k]*W[n,k]+bias) -
template<int MODE>
__global__ __launch_bounds__(256, 2)
void proj_m(const float* __restrict__ X, const float* __restrict__ W,
            const float* __restrict__ bias, float* __restrict__ OUT)
{
  __shared__ unsigned short Ah[128*64];
  __shared__ unsigned short Al[128*64];
  __shared__ unsigned short Bh[128*64];
  __shared__ unsigned short Bl[128*64];
  char* AhB=(char*)Ah; char* AlB=(char*)Al; char* BhB=(char*)Bh; char* BlB=(char*)Bl;
  const int tid  = threadIdx.x;
  const int lane = tid & 63;
  const int wave = tid >> 6;
  const int m0 = blockIdx.y * 128;
  const int n0 = blockIdx.x * 128;
  const int wm = (wave >> 1) * 64;
  const int wn = (wave & 1) * 64;
  const int fr = lane & 15;
  const int fq = lane >> 4;

  f32x4 acc[4][4];
  #pragma unroll
  for (int i=0;i<4;++i)
    #pragma unroll
    for (int j=0;j<4;++j) acc[i][j] = (f32x4){0.f,0.f,0.f,0.f};

  for (int kt = 0; kt < D_DIM/64; ++kt) {
    #pragma unroll
    for (int c = 0; c < 4; ++c) {
      int idx = tid + c*256;
      int row = idx >> 3;
      int k8  = idx & 7;
      const float* ga = X + (size_t)(m0+row)*D_DIM + kt*64 + k8*8;
      const float* gb = W + (size_t)(n0+row)*D_DIM + kt*64 + k8*8;
      f32x4 a0 = *(const f32x4*)ga, a1 = *(const f32x4*)(ga+4);
      f32x4 b0 = *(const f32x4*)gb, b1 = *(const f32x4*)(gb+4);
      bf16x8 vah, val, vbh, vbl;
      #pragma unroll
      for (int j=0;j<4;++j){
        unsigned short h;
        h = f2b(a0[j]); vah[j]   = (short)h; val[j]   = (short)f2b(a0[j]-b2f(h));
        h = f2b(a1[j]); vah[4+j] = (short)h; val[4+j] = (short)f2b(a1[j]-b2f(h));
        h = f2b(b0[j]); vbh[j]   = (short)h; vbl[j]   = (short)f2b(b0[j]-b2f(h));
        h = f2b(b1[j]); vbh[4+j] = (short)h; vbl[4+j] = (short)f2b(b1[j]-b2f(h));
      }
      int lb = row*128 + ((k8*16) ^ ((row&7)<<4));
      *(bf16x8*)(AhB + lb) = vah;
      *(bf16x8*)(AlB + lb) = val;
      *(bf16x8*)(BhB + lb) = vbh;
      *(bf16x8*)(BlB + lb) = vbl;
    }
    __syncthreads();
    #pragma unroll
    for (int kk=0; kk<2; ++kk) {
      bf16x8 afh[4], afl[4], bfh[4], bfl[4];
      #pragma unroll
      for (int i=0;i<4;++i){
        int row = wm+i*16+fr;
        int off = row*128 + ((kk*64 + fq*16) ^ ((row&7)<<4));
        afh[i] = *(const bf16x8*)(AhB + off);
        afl[i] = *(const bf16x8*)(AlB + off);
      }
      #pragma unroll
      for (int j=0;j<4;++j){
        int row = wn+j*16+fr;
        int off = row*128 + ((kk*64 + fq*16) ^ ((row&7)<<4));
        bfh[j] = *(const bf16x8*)(BhB + off);
        bfl[j] = *(const bf16x8*)(BlB + off);
      }
      #pragma unroll
      for (int i=0;i<4;++i)
        #pragma unroll
        for (int j=0;j<4;++j){
          acc[i][j] = __builtin_amdgcn_mfma_f32_16x16x32_bf16(afh[i], bfh[j], acc[i][j], 0,0,0);
          acc[i][j] = __builtin_amdgcn_mfma_f32_16x16x32_bf16(afh[i], bfl[j], acc[i][j], 0,0,0);
          acc[i][j] = __builtin_amdgcn_mfma_f32_16x16x32_bf16(afl[i], bfh[j], acc[i][j], 0,0,0);
        }
    }
    __syncthreads();
  }
  #pragma unroll
  for (int j=0;j<4;++j) {
    int col = n0 + wn + j*16 + fr;
    float bv = bias[col];
    #pragma unroll
    for (int i=0;i<4;++i) {
      int rowb = m0 + wm + i*16 + fq*4;
      #pragma unroll
      for (int r=0;r<4;++r) {
        float v = acc[i][j][r] + bv;
        if (MODE==1) v = 1.f/(1.f + expf(-v));
        OUT[(size_t)(rowb+r)*D_DIM + col] = v;
      }
    }
  }
}

// ---- persistent recurrence ----------------------------------------------------
__global__ __launch_bounds__(256, 1)
void rnn_persist(const float* __restrict__ Wh,
                 float* PO,                 // out_o: G (read) / out (write)
                 float* PH,                 // out_h: P (read@t+1 slot) / h (write)
                 float* __restrict__ h_ex,  // [4 grp][2 buf][8 b][1024] f32
                 uint32_t* __restrict__ flags)  // [4][64] stride 16 u32
{
  __shared__ float hs[8][1024];      // staged h for this group's 8 b's (32KB)
  __shared__ float part[32][8][17];  // k-partials, padded (17KB)

  const int tid = threadIdx.x;
  const int blk = blockIdx.x;
  const int xcd = blk & 7;
  const int g   = xcd >> 1;                       // chain-group 0..3
  const int sl  = ((blk >> 3) << 1) | (xcd & 1);  // e-slice 0..63
  const int e0  = sl * 16;
  const int b0  = g * 8;
  const int kc  = tid >> 3;      // k-chunk 0..31 (32 k each)
  const int el2 = tid & 7;       // e-pair 0..7

  // ---- one-time: Wh slice into registers (2 e-cols x 32 k per thread) ----
  float wh[2][32];
  #pragma unroll
  for (int u = 0; u < 2; ++u) {
    const f32x4* wp = (const f32x4*)(Wh + (size_t)(e0 + 2*el2 + u)*D_DIM + kc*32);
    #pragma unroll
    for (int i = 0; i < 8; ++i) {
      f32x4 v = wp[i];
      wh[u][i*4+0]=v[0]; wh[u][i*4+1]=v[1]; wh[u][i*4+2]=v[2]; wh[u][i*4+3]=v[3];
    }
  }

  const int bl = (tid >> 4) & 7;   // epilogue roles (tid<128)
  const int el = tid & 15;

  for (int t = 0; t < T_DIM; ++t) {
    // prefetch P (out_h slot t+1) and G (out_o slot t) — hidden under poll+stage
    size_t idx_out = (size_t)t*32768 + (size_t)(b0 + bl)*D_DIM + e0 + el;
    float Pv = 0.f, Gv = 0.f;
    if (tid < 128) {
      Pv = PH[idx_out + 32768];
      Gv = PO[idx_out];
    }

    // wait for this group's 64 producers to finish step t-1
    if (t > 0 && tid < 64) {
      const uint32_t* fp = flags + (size_t)(g*64 + tid)*16;
      while (__hip_atomic_load(fp, __ATOMIC_ACQUIRE, __HIP_MEMORY_SCOPE_AGENT)
             < (uint32_t)t)
        __builtin_amdgcn_s_sleep(4);
    }
    __syncthreads();

    // stage h[b0..b0+8][0..1024] from h_ex[g][t&1]
    {
      const float* hsrc = h_ex + (size_t)(g*2 + (t&1))*8192;
      #pragma unroll
      for (int i = 0; i < 32; ++i) {
        int idx = i*256 + tid;
        ((float*)hs)[idx] = __hip_atomic_load(hsrc + idx, __ATOMIC_RELAXED,
                                              __HIP_MEMORY_SCOPE_AGENT);
      }
    }
    __syncthreads();

    // compute: acc[b][u] = sum over this thread's 32-k chunk
    float acc[8][2];
    #pragma unroll
    for (int b = 0; b < 8; ++b) { acc[b][0] = 0.f; acc[b][1] = 0.f; }
    #pragma unroll
    for (int i = 0; i < 8; ++i) {
      #pragma unroll
      for (int b = 0; b < 8; ++b) {
        f32x4 hv = *(const f32x4*)&hs[b][kc*32 + i*4];
        #pragma unroll
        for (int c = 0; c < 4; ++c) {
          acc[b][0] += hv[c]*wh[0][i*4+c];
          acc[b][1] += hv[c]*wh[1][i*4+c];
        }
      }
    }
    #pragma unroll
    for (int b = 0; b < 8; ++b) {
      part[kc][b][2*el2+0] = acc[b][0];
      part[kc][b][2*el2+1] = acc[b][1];
    }
    __syncthreads();

    // reduce + epilogue (tid<128: one (b,e) each)
    if (tid < 128) {
      float pre = 0.f;
      #pragma unroll
      for (int q = 0; q < 32; ++q) pre += part[q][bl][el];
      pre += Pv;
      float th = tanhf(pre);
      float hold = hs[bl][e0 + el];
      float hn = hold + Gv*th;
      float sg = 1.f/(1.f + expf(-hn));
      PO[idx_out] = hn*hn*sg;              // out[t]
      PH[idx_out + 32768] = hn;            // h[t+1] (overwrites P slot)
      __hip_atomic_store(h_ex + (size_t)(g*2 + ((t+1)&1))*8192 + bl*1024 + e0 + el,
                         hn, __ATOMIC_RELAXED, __HIP_MEMORY_SCOPE_AGENT);
    }
    __syncthreads();   // drains h_ex stores (vmcnt(0) before barrier)

    if (tid == 0)
      __hip_atomic_store(flags + (size_t)(g*64 + sl)*16, (uint32_t)(t+1),
                         __ATOMIC_RELEASE, __HIP_MEMORY_SCOPE_AGENT);
  }
}

extern "C" void kernel_launch(void* const* d_in, const int* in_sizes, int n_in,
                              void* d_out, int out_size, void* d_ws, size_t ws_size,
                              hipStream_t stream) {
  const float* x  = (const float*)d_in[0];
  const float* Wh = (const float*)d_in[1];
  const float* Wx = (const float*)d_in[2];
  const float* Wg = (const float*)d_in[3];
  const float* b  = (const float*)d_in[4];
  const float* bg = (const float*)d_in[5];

  float* out_o = (float*)d_out;                       // [T,B,D] fp32
  float* out_h = out_o + (size_t)M_DIM*D_DIM;         // [T+1,B,D] fp32

  char* ws = (char*)d_ws;
  float*    h_ex  = (float*)ws;                       // 256 KB
  uint32_t* flags = (uint32_t*)(ws + (256<<10));      // 16 KB

  init_kernel<<<128, 256, 0, stream>>>(out_h, h_ex, flags);
  proj_m<1><<<dim3(8,128), 256, 0, stream>>>(x, Wg, bg, out_o);           // G -> out_o[t]
  proj_m<0><<<dim3(8,128), 256, 0, stream>>>(x, Wx, b,  out_h + 32768);   // P -> out_h[t+1]
  rnn_persist<<<256, 256, 0, stream>>>(Wh, out_o, out_h, h_ex, flags);
}

// Round 9
// 3279.955 us; speedup vs baseline: 5.9823x; 2.9543x over previous
//
#include <hip/hip_runtime.h>
#include <hip/hip_bf16.h>
#include <stdint.h>

// E60bGatedResidualCell — R9: persistent rnn, pipelined coherent staging.
// out[t] = h²σ(h); h_{t+1} = h_t + g_t ⊙ tanh(h_t W_hᵀ + x_t W_xᵀ + b)
// fp32 outputs. P in out_h[t+1] (read@t pre-overwrite), G in out_o[t] (same).
// 256 WGs = 8 chain-groups (4 b) × 32 e-slices (32 e). Wh in VGPRs (128 f32/thr).
// Cross-WG h: inline-asm global_load/store_dwordx4 `sc0 sc1` (per-access coherent,
// pipelined — fixes R8's 32 serialized atomic-load round trips) + flag atomics.
// hs XOR-swizzled (kills R8's 1.68e8 bank conflicts); h_old in register.

#define T_DIM 512
#define B_DIM 32
#define D_DIM 1024
#define M_DIM (T_DIM*B_DIM)

typedef __attribute__((ext_vector_type(4))) float f32x4;
typedef __attribute__((ext_vector_type(8))) short bf16x8;

__device__ inline unsigned short f2b(float f){
  union { float f; uint32_t u; } c; c.f = f;
  uint32_t u = c.u + 0x7fffu + ((c.u >> 16) & 1u);   // RNE
  return (unsigned short)(u >> 16);
}
__device__ inline float b2f(unsigned short h){
  union { uint32_t u; float f; } c; c.u = ((uint32_t)h) << 16;
  return c.f;
}

// ---- init: zero out_h[0], h_ex buf0 of each group, flags ----------------------
__global__ void init_kernel(float* __restrict__ out_h0,
                            float* __restrict__ h_ex,
                            uint32_t* __restrict__ flags){
  int i = blockIdx.x*blockDim.x + threadIdx.x;   // 0..32767
  out_h0[i] = 0.f;
  int g = i >> 12, j = i & 4095;
  h_ex[(size_t)g*8192 + j] = 0.f;                // buf0 of each of 8 groups
  if (i < 4096) flags[i] = 0;
}

// ---- proj (split-bf16 MFMA, fp32 out): OUT[m,n] = f(sum_k X[m,k]*W[n,k]+bias) -
template<int MODE>
__global__ __launch_bounds__(256, 2)
void proj_m(const float* __restrict__ X, const float* __restrict__ W,
            const float* __restrict__ bias, float* __restrict__ OUT)
{
  __shared__ unsigned short Ah[128*64];
  __shared__ unsigned short Al[128*64];
  __shared__ unsigned short Bh[128*64];
  __shared__ unsigned short Bl[128*64];
  char* AhB=(char*)Ah; char* AlB=(char*)Al; char* BhB=(char*)Bh; char* BlB=(char*)Bl;
  const int tid  = threadIdx.x;
  const int lane = tid & 63;
  const int wave = tid >> 6;
  const int m0 = blockIdx.y * 128;
  const int n0 = blockIdx.x * 128;
  const int wm = (wave >> 1) * 64;
  const int wn = (wave & 1) * 64;
  const int fr = lane & 15;
  const int fq = lane >> 4;

  f32x4 acc[4][4];
  #pragma unroll
  for (int i=0;i<4;++i)
    #pragma unroll
    for (int j=0;j<4;++j) acc[i][j] = (f32x4){0.f,0.f,0.f,0.f};

  for (int kt = 0; kt < D_DIM/64; ++kt) {
    #pragma unroll
    for (int c = 0; c < 4; ++c) {
      int idx = tid + c*256;
      int row = idx >> 3;
      int k8  = idx & 7;
      const float* ga = X + (size_t)(m0+row)*D_DIM + kt*64 + k8*8;
      const float* gb = W + (size_t)(n0+row)*D_DIM + kt*64 + k8*8;
      f32x4 a0 = *(const f32x4*)ga, a1 = *(const f32x4*)(ga+4);
      f32x4 b0 = *(const f32x4*)gb, b1 = *(const f32x4*)(gb+4);
      bf16x8 vah, val, vbh, vbl;
      #pragma unroll
      for (int j=0;j<4;++j){
        unsigned short h;
        h = f2b(a0[j]); vah[j]   = (short)h; val[j]   = (short)f2b(a0[j]-b2f(h));
        h = f2b(a1[j]); vah[4+j] = (short)h; val[4+j] = (short)f2b(a1[j]-b2f(h));
        h = f2b(b0[j]); vbh[j]   = (short)h; vbl[j]   = (short)f2b(b0[j]-b2f(h));
        h = f2b(b1[j]); vbh[4+j] = (short)h; vbl[4+j] = (short)f2b(b1[j]-b2f(h));
      }
      int lb = row*128 + ((k8*16) ^ ((row&7)<<4));
      *(bf16x8*)(AhB + lb) = vah;
      *(bf16x8*)(AlB + lb) = val;
      *(bf16x8*)(BhB + lb) = vbh;
      *(bf16x8*)(BlB + lb) = vbl;
    }
    __syncthreads();
    #pragma unroll
    for (int kk=0; kk<2; ++kk) {
      bf16x8 afh[4], afl[4], bfh[4], bfl[4];
      #pragma unroll
      for (int i=0;i<4;++i){
        int row = wm+i*16+fr;
        int off = row*128 + ((kk*64 + fq*16) ^ ((row&7)<<4));
        afh[i] = *(const bf16x8*)(AhB + off);
        afl[i] = *(const bf16x8*)(AlB + off);
      }
      #pragma unroll
      for (int j=0;j<4;++j){
        int row = wn+j*16+fr;
        int off = row*128 + ((kk*64 + fq*16) ^ ((row&7)<<4));
        bfh[j] = *(const bf16x8*)(BhB + off);
        bfl[j] = *(const bf16x8*)(BlB + off);
      }
      #pragma unroll
      for (int i=0;i<4;++i)
        #pragma unroll
        for (int j=0;j<4;++j){
          acc[i][j] = __builtin_amdgcn_mfma_f32_16x16x32_bf16(afh[i], bfh[j], acc[i][j], 0,0,0);
          acc[i][j] = __builtin_amdgcn_mfma_f32_16x16x32_bf16(afh[i], bfl[j], acc[i][j], 0,0,0);
          acc[i][j] = __builtin_amdgcn_mfma_f32_16x16x32_bf16(afl[i], bfh[j], acc[i][j], 0,0,0);
        }
    }
    __syncthreads();
  }
  #pragma unroll
  for (int j=0;j<4;++j) {
    int col = n0 + wn + j*16 + fr;
    float bv = bias[col];
    #pragma unroll
    for (int i=0;i<4;++i) {
      int rowb = m0 + wm + i*16 + fq*4;
      #pragma unroll
      for (int r=0;r<4;++r) {
        float v = acc[i][j][r] + bv;
        if (MODE==1) v = 1.f/(1.f + expf(-v));
        OUT[(size_t)(rowb+r)*D_DIM + col] = v;
      }
    }
  }
}

// ---- persistent recurrence ----------------------------------------------------
__global__ __launch_bounds__(256, 1)
void rnn_persist(const float* __restrict__ Wh,
                 float* PO,                 // out_o: G (read) / out (write)
                 float* PH,                 // out_h: P (read@t+1 slot) / h (write)
                 float* __restrict__ h_ex,  // [8 grp][2 buf][4096 f32]
                 uint32_t* __restrict__ flags)  // [8][32] stride 16 u32
{
  __shared__ char  hsb[4*4096];          // h staged, XOR-swizzled 16B granules (16KB)
  __shared__ float part[16*137];         // k-partials, padded stride (8.8KB)

  const int tid = threadIdx.x;
  const int blk = blockIdx.x;
  const int g   = blk & 7;               // chain-group 0..7 (XCD-interleaved)
  const int sl  = blk >> 3;              // e-slice 0..31
  const int e0  = sl * 32;
  const int b0  = g * 4;
  const int e2  = tid & 15;              // e-pair 0..15
  const int kc  = tid >> 4;              // k-chunk 0..15 (64 k each)

  // ---- one-time: Wh slice into registers (2 e-cols x 64 k per thread) ----
  f32x4 wh0[16], wh1[16];
  {
    const f32x4* wp0 = (const f32x4*)(Wh + (size_t)(e0 + 2*e2 + 0)*D_DIM + kc*64);
    const f32x4* wp1 = (const f32x4*)(Wh + (size_t)(e0 + 2*e2 + 1)*D_DIM + kc*64);
    #pragma unroll
    for (int i = 0; i < 16; ++i) { wh0[i] = wp0[i]; wh1[i] = wp1[i]; }
  }

  const int bl = tid >> 5;               // epilogue roles (tid<128): b 0..3
  const int el = tid & 31;               // e 0..31
  float hold = 0.f;                      // this thread's own h[b0+bl][e0+el]

  for (int t = 0; t < T_DIM; ++t) {
    // prefetch P (out_h slot t+1) and G (out_o slot t) — independent of flags
    size_t idx_out = (size_t)t*32768 + (size_t)(b0 + bl)*D_DIM + e0 + el;
    float Pv = 0.f, Gv = 0.f;
    if (tid < 128) {
      Pv = PH[idx_out + 32768];
      Gv = PO[idx_out];
    }

    // wait for this group's 32 producers to finish step t-1
    if (t > 0 && tid < 32) {
      const uint32_t* fp = flags + (size_t)(g*32 + tid)*16;
      while (__hip_atomic_load(fp, __ATOMIC_RELAXED, __HIP_MEMORY_SCOPE_AGENT)
             < (uint32_t)t)
        __builtin_amdgcn_s_sleep(2);
    }
    __syncthreads();

    // stage h[4][1024] from h_ex[g][t&1] — pipelined coherent 16B loads
    {
      const char* hsrc = (const char*)(h_ex + (size_t)(g*2 + (t&1))*4096) + tid*16;
      f32x4 r0, r1, r2, r3;
      asm volatile("global_load_dwordx4 %0, %1, off sc0 sc1"
                   : "=v"(r0) : "v"(hsrc)          : "memory");
      asm volatile("global_load_dwordx4 %0, %1, off sc0 sc1"
                   : "=v"(r1) : "v"(hsrc + 4096)   : "memory");
      asm volatile("global_load_dwordx4 %0, %1, off sc0 sc1"
                   : "=v"(r2) : "v"(hsrc + 8192)   : "memory");
      asm volatile("global_load_dwordx4 %0, %1, off sc0 sc1"
                   : "=v"(r3) : "v"(hsrc + 12288)  : "memory");
      asm volatile("s_waitcnt vmcnt(0)" ::: "memory");
      __builtin_amdgcn_sched_barrier(0);
      // scatter to LDS with XOR swizzle: granule g16 -> g16 ^ (g16>>4), per b-plane
      #pragma unroll
      for (int i = 0; i < 4; ++i) {
        int G   = i*256 + tid;
        int bq  = G >> 8;
        int g16 = G & 255;
        int g16s = g16 ^ (g16 >> 4);
        f32x4 v = (i==0) ? r0 : (i==1) ? r1 : (i==2) ? r2 : r3;
        *(f32x4*)(hsb + bq*4096 + g16s*16) = v;
      }
    }
    __syncthreads();

    // compute: acc[b][u] = sum over this thread's 64-k chunk (conflict-free reads)
    float acc[4][2];
    #pragma unroll
    for (int b = 0; b < 4; ++b) { acc[b][0] = 0.f; acc[b][1] = 0.f; }
    #pragma unroll
    for (int i = 0; i < 16; ++i) {
      f32x4 w0 = wh0[i], w1 = wh1[i];
      #pragma unroll
      for (int b = 0; b < 4; ++b) {
        f32x4 hv = *(const f32x4*)(hsb + b*4096 + kc*256 + ((i ^ kc) << 4));
        float d0 = hv[0]*w0[0] + hv[1]*w0[1] + hv[2]*w0[2] + hv[3]*w0[3];
        float d1 = hv[0]*w1[0] + hv[1]*w1[1] + hv[2]*w1[2] + hv[3]*w1[3];
        acc[b][0] += d0;
        acc[b][1] += d1;
      }
    }
    #pragma unroll
    for (int b = 0; b < 4; ++b) {
      part[kc*137 + b*32 + 2*e2 + 0] = acc[b][0];
      part[kc*137 + b*32 + 2*e2 + 1] = acc[b][1];
    }
    __syncthreads();

    // reduce + epilogue (tid<128: one (b,e) each)
    if (tid < 128) {
      float pre = 0.f;
      #pragma unroll
      for (int q = 0; q < 16; ++q) pre += part[q*137 + bl*32 + el];
      pre += Pv;
      float th = tanhf(pre);
      float hn = hold + Gv*th;
      hold = hn;
      float sg = 1.f/(1.f + expf(-hn));
      PO[idx_out] = hn*hn*sg;              // out[t]
      PH[idx_out + 32768] = hn;            // h[t+1] (overwrites P slot)
      float* hdst = h_ex + (size_t)(g*2 + ((t+1)&1))*4096 + bl*1024 + e0 + el;
      asm volatile("global_store_dword %0, %1, off sc0 sc1"
                   :: "v"(hdst), "v"(hn) : "memory");
    }
    asm volatile("s_waitcnt vmcnt(0)" ::: "memory");
    __syncthreads();

    if (tid == 0)
      __hip_atomic_store(flags + (size_t)(g*32 + sl)*16, (uint32_t)(t+1),
                         __ATOMIC_RELEASE, __HIP_MEMORY_SCOPE_AGENT);
  }
}

extern "C" void kernel_launch(void* const* d_in, const int* in_sizes, int n_in,
                              void* d_out, int out_size, void* d_ws, size_t ws_size,
                              hipStream_t stream) {
  const float* x  = (const float*)d_in[0];
  const float* Wh = (const float*)d_in[1];
  const float* Wx = (const float*)d_in[2];
  const float* Wg = (const float*)d_in[3];
  const float* b  = (const float*)d_in[4];
  const float* bg = (const float*)d_in[5];

  float* out_o = (float*)d_out;                       // [T,B,D] fp32
  float* out_h = out_o + (size_t)M_DIM*D_DIM;         // [T+1,B,D] fp32

  char* ws = (char*)d_ws;
  float*    h_ex  = (float*)ws;                       // 8*2*16KB = 256 KB
  uint32_t* flags = (uint32_t*)(ws + (256<<10));      // 16 KB

  init_kernel<<<128, 256, 0, stream>>>(out_h, h_ex, flags);
  proj_m<1><<<dim3(8,128), 256, 0, stream>>>(x, Wg, bg, out_o);           // G -> out_o[t]
  proj_m<0><<<dim3(8,128), 256, 0, stream>>>(x, Wx, b,  out_h + 32768);   // P -> out_h[t+1]
  rnn_persist<<<256, 256, 0, stream>>>(Wh, out_o, out_h, h_ex, flags);
}

// Round 10
// 1889.045 us; speedup vs baseline: 10.3872x; 1.7363x over previous
//
#include <hip/hip_runtime.h>
#include <hip/hip_bf16.h>
#include <stdint.h>

// E60bGatedResidualCell — R10: R9 minus the per-step buffer_wbl2.
// out[t] = h²σ(h); h_{t+1} = h_t + g_t ⊙ tanh(h_t W_hᵀ + x_t W_xᵀ + b)
// fp32 outputs. P in out_h[t+1] (read@t pre-overwrite), G in out_o[t] (same).
// 256 WGs = 8 chain-groups (4 b) × 32 e-slices (32 e). Wh in VGPRs (128 f32/thr).
// h exchange: sc0 sc1 write-through stores + vmcnt(0) + barrier, then a PLAIN
// sc0 sc1 flag store (R9's __ATOMIC_RELEASE emitted buffer_wbl2 = L2 flush per
// WG per step — the dominant 3.5µs/step). Poll: RELAXED agent atomic load.

#define T_DIM 512
#define B_DIM 32
#define D_DIM 1024
#define M_DIM (T_DIM*B_DIM)

typedef __attribute__((ext_vector_type(4))) float f32x4;
typedef __attribute__((ext_vector_type(8))) short bf16x8;

__device__ inline unsigned short f2b(float f){
  union { float f; uint32_t u; } c; c.f = f;
  uint32_t u = c.u + 0x7fffu + ((c.u >> 16) & 1u);   // RNE
  return (unsigned short)(u >> 16);
}
__device__ inline float b2f(unsigned short h){
  union { uint32_t u; float f; } c; c.u = ((uint32_t)h) << 16;
  return c.f;
}

// ---- init: zero out_h[0], h_ex buf0 of each group, flags ----------------------
__global__ void init_kernel(float* __restrict__ out_h0,
                            float* __restrict__ h_ex,
                            uint32_t* __restrict__ flags){
  int i = blockIdx.x*blockDim.x + threadIdx.x;   // 0..32767
  out_h0[i] = 0.f;
  int g = i >> 12, j = i & 4095;
  h_ex[(size_t)g*8192 + j] = 0.f;                // buf0 of each of 8 groups
  if (i < 4096) flags[i] = 0;
}

// ---- proj (split-bf16 MFMA, fp32 out): OUT[m,n] = f(sum_k X[m,k]*W[n,k]+bias) -
template<int MODE>
__global__ __launch_bounds__(256, 2)
void proj_m(const float* __restrict__ X, const float* __restrict__ W,
            const float* __restrict__ bias, float* __restrict__ OUT)
{
  __shared__ unsigned short Ah[128*64];
  __shared__ unsigned short Al[128*64];
  __shared__ unsigned short Bh[128*64];
  __shared__ unsigned short Bl[128*64];
  char* AhB=(char*)Ah; char* AlB=(char*)Al; char* BhB=(char*)Bh; char* BlB=(char*)Bl;
  const int tid  = threadIdx.x;
  const int lane = tid & 63;
  const int wave = tid >> 6;
  const int m0 = blockIdx.y * 128;
  const int n0 = blockIdx.x * 128;
  const int wm = (wave >> 1) * 64;
  const int wn = (wave & 1) * 64;
  const int fr = lane & 15;
  const int fq = lane >> 4;

  f32x4 acc[4][4];
  #pragma unroll
  for (int i=0;i<4;++i)
    #pragma unroll
    for (int j=0;j<4;++j) acc[i][j] = (f32x4){0.f,0.f,0.f,0.f};

  for (int kt = 0; kt < D_DIM/64; ++kt) {
    #pragma unroll
    for (int c = 0; c < 4; ++c) {
      int idx = tid + c*256;
      int row = idx >> 3;
      int k8  = idx & 7;
      const float* ga = X + (size_t)(m0+row)*D_DIM + kt*64 + k8*8;
      const float* gb = W + (size_t)(n0+row)*D_DIM + kt*64 + k8*8;
      f32x4 a0 = *(const f32x4*)ga, a1 = *(const f32x4*)(ga+4);
      f32x4 b0 = *(const f32x4*)gb, b1 = *(const f32x4*)(gb+4);
      bf16x8 vah, val, vbh, vbl;
      #pragma unroll
      for (int j=0;j<4;++j){
        unsigned short h;
        h = f2b(a0[j]); vah[j]   = (short)h; val[j]   = (short)f2b(a0[j]-b2f(h));
        h = f2b(a1[j]); vah[4+j] = (short)h; val[4+j] = (short)f2b(a1[j]-b2f(h));
        h = f2b(b0[j]); vbh[j]   = (short)h; vbl[j]   = (short)f2b(b0[j]-b2f(h));
        h = f2b(b1[j]); vbh[4+j] = (short)h; vbl[4+j] = (short)f2b(b1[j]-b2f(h));
      }
      int lb = row*128 + ((k8*16) ^ ((row&7)<<4));
      *(bf16x8*)(AhB + lb) = vah;
      *(bf16x8*)(AlB + lb) = val;
      *(bf16x8*)(BhB + lb) = vbh;
      *(bf16x8*)(BlB + lb) = vbl;
    }
    __syncthreads();
    #pragma unroll
    for (int kk=0; kk<2; ++kk) {
      bf16x8 afh[4], afl[4], bfh[4], bfl[4];
      #pragma unroll
      for (int i=0;i<4;++i){
        int row = wm+i*16+fr;
        int off = row*128 + ((kk*64 + fq*16) ^ ((row&7)<<4));
        afh[i] = *(const bf16x8*)(AhB + off);
        afl[i] = *(const bf16x8*)(AlB + off);
      }
      #pragma unroll
      for (int j=0;j<4;++j){
        int row = wn+j*16+fr;
        int off = row*128 + ((kk*64 + fq*16) ^ ((row&7)<<4));
        bfh[j] = *(const bf16x8*)(BhB + off);
        bfl[j] = *(const bf16x8*)(BlB + off);
      }
      #pragma unroll
      for (int i=0;i<4;++i)
        #pragma unroll
        for (int j=0;j<4;++j){
          acc[i][j] = __builtin_amdgcn_mfma_f32_16x16x32_bf16(afh[i], bfh[j], acc[i][j], 0,0,0);
          acc[i][j] = __builtin_amdgcn_mfma_f32_16x16x32_bf16(afh[i], bfl[j], acc[i][j], 0,0,0);
          acc[i][j] = __builtin_amdgcn_mfma_f32_16x16x32_bf16(afl[i], bfh[j], acc[i][j], 0,0,0);
        }
    }
    __syncthreads();
  }
  #pragma unroll
  for (int j=0;j<4;++j) {
    int col = n0 + wn + j*16 + fr;
    float bv = bias[col];
    #pragma unroll
    for (int i=0;i<4;++i) {
      int rowb = m0 + wm + i*16 + fq*4;
      #pragma unroll
      for (int r=0;r<4;++r) {
        float v = acc[i][j][r] + bv;
        if (MODE==1) v = 1.f/(1.f + expf(-v));
        OUT[(size_t)(rowb+r)*D_DIM + col] = v;
      }
    }
  }
}

// ---- persistent recurrence ----------------------------------------------------
__global__ __launch_bounds__(256, 1)
void rnn_persist(const float* __restrict__ Wh,
                 float* PO,                 // out_o: G (read) / out (write)
                 float* PH,                 // out_h: P (read@t+1 slot) / h (write)
                 float* __restrict__ h_ex,  // [8 grp][2 buf][4096 f32]
                 uint32_t* __restrict__ flags)  // [8][32] stride 16 u32
{
  __shared__ char  hsb[4*4096];          // h staged, XOR-swizzled 16B granules (16KB)
  __shared__ float part[16*137];         // k-partials, padded stride (8.8KB)

  const int tid = threadIdx.x;
  const int blk = blockIdx.x;
  const int g   = blk & 7;               // chain-group 0..7 (XCD-interleaved)
  const int sl  = blk >> 3;              // e-slice 0..31
  const int e0  = sl * 32;
  const int b0  = g * 4;
  const int e2  = tid & 15;              // e-pair 0..15
  const int kc  = tid >> 4;              // k-chunk 0..15 (64 k each)

  // ---- one-time: Wh slice into registers (2 e-cols x 64 k per thread) ----
  f32x4 wh0[16], wh1[16];
  {
    const f32x4* wp0 = (const f32x4*)(Wh + (size_t)(e0 + 2*e2 + 0)*D_DIM + kc*64);
    const f32x4* wp1 = (const f32x4*)(Wh + (size_t)(e0 + 2*e2 + 1)*D_DIM + kc*64);
    #pragma unroll
    for (int i = 0; i < 16; ++i) { wh0[i] = wp0[i]; wh1[i] = wp1[i]; }
  }

  const int bl = tid >> 5;               // epilogue roles (tid<128): b 0..3
  const int el = tid & 31;               // e 0..31
  float hold = 0.f;                      // this thread's own h[b0+bl][e0+el]

  for (int t = 0; t < T_DIM; ++t) {
    // prefetch P (out_h slot t+1) and G (out_o slot t) — independent of flags
    size_t idx_out = (size_t)t*32768 + (size_t)(b0 + bl)*D_DIM + e0 + el;
    float Pv = 0.f, Gv = 0.f;
    if (tid < 128) {
      Pv = PH[idx_out + 32768];
      Gv = PO[idx_out];
    }

    // wait for this group's 32 producers to finish step t-1
    if (t > 0 && tid < 32) {
      const uint32_t* fp = flags + (size_t)(g*32 + tid)*16;
      while (__hip_atomic_load(fp, __ATOMIC_RELAXED, __HIP_MEMORY_SCOPE_AGENT)
             < (uint32_t)t)
        __builtin_amdgcn_s_sleep(1);
    }
    __syncthreads();

    // stage h[4][1024] from h_ex[g][t&1] — pipelined coherent 16B loads
    {
      const char* hsrc = (const char*)(h_ex + (size_t)(g*2 + (t&1))*4096) + tid*16;
      f32x4 r0, r1, r2, r3;
      asm volatile("global_load_dwordx4 %0, %1, off sc0 sc1"
                   : "=v"(r0) : "v"(hsrc)          : "memory");
      asm volatile("global_load_dwordx4 %0, %1, off sc0 sc1"
                   : "=v"(r1) : "v"(hsrc + 4096)   : "memory");
      asm volatile("global_load_dwordx4 %0, %1, off sc0 sc1"
                   : "=v"(r2) : "v"(hsrc + 8192)   : "memory");
      asm volatile("global_load_dwordx4 %0, %1, off sc0 sc1"
                   : "=v"(r3) : "v"(hsrc + 12288)  : "memory");
      asm volatile("s_waitcnt vmcnt(0)" ::: "memory");
      __builtin_amdgcn_sched_barrier(0);
      // scatter to LDS with XOR swizzle: granule g16 -> g16 ^ (g16>>4), per b-plane
      #pragma unroll
      for (int i = 0; i < 4; ++i) {
        int G   = i*256 + tid;
        int bq  = G >> 8;
        int g16 = G & 255;
        int g16s = g16 ^ (g16 >> 4);
        f32x4 v = (i==0) ? r0 : (i==1) ? r1 : (i==2) ? r2 : r3;
        *(f32x4*)(hsb + bq*4096 + g16s*16) = v;
      }
    }
    __syncthreads();

    // compute: acc[b][u] = sum over this thread's 64-k chunk (conflict-free reads)
    float acc[4][2];
    #pragma unroll
    for (int b = 0; b < 4; ++b) { acc[b][0] = 0.f; acc[b][1] = 0.f; }
    #pragma unroll
    for (int i = 0; i < 16; ++i) {
      f32x4 w0 = wh0[i], w1 = wh1[i];
      #pragma unroll
      for (int b = 0; b < 4; ++b) {
        f32x4 hv = *(const f32x4*)(hsb + b*4096 + kc*256 + ((i ^ kc) << 4));
        float d0 = hv[0]*w0[0] + hv[1]*w0[1] + hv[2]*w0[2] + hv[3]*w0[3];
        float d1 = hv[0]*w1[0] + hv[1]*w1[1] + hv[2]*w1[2] + hv[3]*w1[3];
        acc[b][0] += d0;
        acc[b][1] += d1;
      }
    }
    #pragma unroll
    for (int b = 0; b < 4; ++b) {
      part[kc*137 + b*32 + 2*e2 + 0] = acc[b][0];
      part[kc*137 + b*32 + 2*e2 + 1] = acc[b][1];
    }
    __syncthreads();

    // reduce + epilogue (tid<128: one (b,e) each)
    if (tid < 128) {
      float pre = 0.f;
      #pragma unroll
      for (int q = 0; q < 16; ++q) pre += part[q*137 + bl*32 + el];
      pre += Pv;
      float th = tanhf(pre);
      float hn = hold + Gv*th;
      hold = hn;
      float sg = 1.f/(1.f + expf(-hn));
      PO[idx_out] = hn*hn*sg;              // out[t]
      PH[idx_out + 32768] = hn;            // h[t+1] (overwrites P slot)
      float* hdst = h_ex + (size_t)(g*2 + ((t+1)&1))*4096 + bl*1024 + e0 + el;
      asm volatile("global_store_dword %0, %1, off sc0 sc1"
                   :: "v"(hdst), "v"(hn) : "memory");
    }
    asm volatile("s_waitcnt vmcnt(0)" ::: "memory");
    __syncthreads();

    // flag release: data already ACKed at LLC (sc0 sc1 + vmcnt(0) + barrier),
    // so a plain coherent store suffices — NO buffer_wbl2 (the R9 cost).
    if (tid == 0) {
      uint32_t fv = (uint32_t)(t+1);
      uint32_t* fptr = flags + (size_t)(g*32 + sl)*16;
      asm volatile("global_store_dword %0, %1, off sc0 sc1"
                   :: "v"(fptr), "v"(fv) : "memory");
    }
  }
}

extern "C" void kernel_launch(void* const* d_in, const int* in_sizes, int n_in,
                              void* d_out, int out_size, void* d_ws, size_t ws_size,
                              hipStream_t stream) {
  const float* x  = (const float*)d_in[0];
  const float* Wh = (const float*)d_in[1];
  const float* Wx = (const float*)d_in[2];
  const float* Wg = (const float*)d_in[3];
  const float* b  = (const float*)d_in[4];
  const float* bg = (const float*)d_in[5];

  float* out_o = (float*)d_out;                       // [T,B,D] fp32
  float* out_h = out_o + (size_t)M_DIM*D_DIM;         // [T+1,B,D] fp32

  char* ws = (char*)d_ws;
  float*    h_ex  = (float*)ws;                       // 8*2*16KB = 256 KB
  uint32_t* flags = (uint32_t*)(ws + (256<<10));      // 16 KB

  init_kernel<<<128, 256, 0, stream>>>(out_h, h_ex, flags);
  proj_m<1><<<dim3(8,128), 256, 0, stream>>>(x, Wg, bg, out_o);           // G -> out_o[t]
  proj_m<0><<<dim3(8,128), 256, 0, stream>>>(x, Wx, b,  out_h + 32768);   // P -> out_h[t+1]
  rnn_persist<<<256, 256, 0, stream>>>(Wh, out_o, out_h, h_ex, flags);
}